// Round 2
// baseline (98.979 us; speedup 1.0000x reference)
//
#include <hip/hip_runtime.h>
#include <hip/hip_bf16.h>

// ConvPolicy14: tiny 1D conv encoder-decoder, batch=1, IN_DIM=93. FP32 in/out
// (reference declares jnp.float32 everywhere). Entire network in ONE kernel,
// ONE wave (64 threads). All params + x staged to LDS in a single cooperative
// load phase (one HBM latency round); each layer computed with one lane per
// output element; __syncthreads() (cheap for a 1-wave block) between layers.
//
// Deconv identity (from _deconv1d's flip+transpose+pad):
//   y[o,p] = b[o] + sum_i sum_j w[i,o,j] * in[i, p + pad - j]   (bounds-checked)

__global__ __launch_bounds__(64, 1) void convpolicy14_kernel(
    const float* __restrict__ x,
    const float* __restrict__ w1c, const float* __restrict__ b1c,
    const float* __restrict__ w2c, const float* __restrict__ b2c,
    const float* __restrict__ w3c, const float* __restrict__ b3c,
    const float* __restrict__ w4c, const float* __restrict__ b4c,
    const float* __restrict__ dw1, const float* __restrict__ db1,
    const float* __restrict__ dw2, const float* __restrict__ db2,
    const float* __restrict__ dw3, const float* __restrict__ db3,
    const float* __restrict__ dw4, const float* __restrict__ db4,
    float* __restrict__ out)
{
    // ---- LDS: all params/x (918 fp32), plus activations ----
    __shared__ float P[918];
    __shared__ float jcat[84];                 // 12 ch x 7
    __shared__ float ext[3];
    __shared__ float c1[28], c2[28];           // 4 x 7
    __shared__ float dsb[12], c3[12];          // 4 x 3
    __shared__ float comb[3];
    __shared__ float dc1[12], dc2[12];         // 4 x 3
    __shared__ float dc3[28];                  // 4 x 7

    const int t = threadIdx.x;

    // ---- Phase 0: stage all 17 arrays to LDS, one latency round ----
    {
        const float* srcs[17] = {x, w1c, b1c, w2c, b2c, w3c, b3c, w4c, b4c,
                                 dw1, db1, dw2, db2, dw3, db3, dw4, db4};
        const int offs[18] = {0, 93, 237, 241, 289, 293, 341, 345, 381, 384,
                              420, 424, 520, 524, 620, 624, 912, 918};
        #pragma unroll
        for (int a = 0; a < 17; ++a) {
            const int base = offs[a];
            const int n    = offs[a + 1] - base;
            for (int i = t; i < n; i += 64)
                P[base + i] = srcs[a][i];
        }
    }
    __syncthreads();

    const float* X   = P + 0;    // 93
    const float* W1  = P + 93;   // (4,12,3)
    const float* B1  = P + 237;  // (4,)
    const float* W2  = P + 241;  // (4,4,3)
    const float* B2  = P + 289;
    const float* W3  = P + 293;  // (4,4,3)
    const float* B3  = P + 341;
    const float* W4  = P + 345;  // (3,4,3)
    const float* B4  = P + 381;  // (3,)
    const float* DW1 = P + 384;  // (3,4,3)
    const float* DB1 = P + 420;  // (4,)
    const float* DW2 = P + 424;  // (8,4,3)
    const float* DB2 = P + 520;
    const float* DW3 = P + 524;  // (8,4,3)
    const float* DB3 = P + 620;
    const float* DW4 = P + 624;  // (16,6,3)
    const float* DB4 = P + 912;  // (6,)

    // ---- Phase 1: build jcat (12x7) and ext_obs ----
    for (int idx = t; idx < 84; idx += 64) {
        const int c = idx / 7, p = idx % 7;
        float v;
        if (c < 6) { const int f = c * 7 + p;        v = (f < 2) ? 0.0f : X[f + 5];  }  // jl:  x[7:47]
        else       { const int f = (c - 6) * 7 + p;  v = (f < 2) ? 0.0f : X[f + 51]; }  // jdl: x[53:93]
        jcat[idx] = v;
    }
    if (t == 0) {
        const float qw = X[3], qx = X[4], qy = X[5], qz = X[6];
        ext[0] = atan2f(qz, qw) - atan2f(-qx, qy);
        ext[1] = X[47];   // obsd[0,0]
        ext[2] = X[52];   // obsd[0,5]
    }
    __syncthreads();

    // ---- conv1: (12,7) -> (4,7), pad 1, tanh ----
    if (t < 28) {
        const int o = t / 7, p = t % 7;
        float acc = B1[o];
        #pragma unroll
        for (int i = 0; i < 12; ++i) {
            const float* w = &W1[(o * 12 + i) * 3];
            const float* r = &jcat[i * 7];
            if (p > 0) acc += w[0] * r[p - 1];
            acc += w[1] * r[p];
            if (p < 6) acc += w[2] * r[p + 1];
        }
        c1[t] = tanhf(acc);
    }
    __syncthreads();

    // ---- conv2: (4,7) -> (4,7), pad 1, tanh ----
    if (t < 28) {
        const int o = t / 7, p = t % 7;
        float acc = B2[o];
        #pragma unroll
        for (int i = 0; i < 4; ++i) {
            const float* w = &W2[(o * 4 + i) * 3];
            const float* r = &c1[i * 7];
            if (p > 0) acc += w[0] * r[p - 1];
            acc += w[1] * r[p];
            if (p < 6) acc += w[2] * r[p + 1];
        }
        c2[t] = tanhf(acc);
    }
    __syncthreads();

    // ---- downsample: overlapping mean windows [0:3],[2:5],[4:7] -> (4,3) ----
    if (t < 12) {
        const int c = t / 3, j = t % 3;
        const float* r = &c2[c * 7 + 2 * j];
        dsb[t] = (r[0] + r[1] + r[2]) * (1.0f / 3.0f);
    }
    __syncthreads();

    // ---- conv3: (4,3) -> (4,3), pad 1, tanh ----
    if (t < 12) {
        const int o = t / 3, p = t % 3;
        float acc = B3[o];
        #pragma unroll
        for (int i = 0; i < 4; ++i) {
            const float* w = &W3[(o * 4 + i) * 3];
            const float* r = &dsb[i * 3];
            if (p > 0) acc += w[0] * r[p - 1];
            acc += w[1] * r[p];
            if (p < 2) acc += w[2] * r[p + 1];
        }
        c3[t] = tanhf(acc);
    }
    __syncthreads();

    // ---- conv4: (4,3) -> (3,1), pad 0, tanh; + ext_obs -> comb ----
    if (t < 3) {
        float acc = B4[t];
        #pragma unroll
        for (int i = 0; i < 4; ++i)
            #pragma unroll
            for (int k = 0; k < 3; ++k)
                acc += W4[(t * 4 + i) * 3 + k] * c3[i * 3 + k];
        comb[t] = tanhf(acc) + ext[t];
    }
    __syncthreads();

    // ---- deconv1: (3,1) -> (4,3), pad 0, tanh.  y[o,p] = sum_i w[i,o,p]*comb[i] ----
    if (t < 12) {
        const int o = t / 3, p = t % 3;
        float acc = DB1[o];
        #pragma unroll
        for (int i = 0; i < 3; ++i)
            acc += DW1[(i * 4 + o) * 3 + p] * comb[i];
        dc1[t] = tanhf(acc);
    }
    __syncthreads();

    // ---- deconv2: cat([dc1, c3]) (8,3) -> (4,3), pad 1, tanh ----
    if (t < 12) {
        const int o = t / 3, p = t % 3;
        float acc = DB2[o];
        #pragma unroll
        for (int i = 0; i < 8; ++i) {
            const float* w = &DW2[(i * 4 + o) * 3];
            const float* r = (i < 4) ? &dc1[i * 3] : &c3[(i - 4) * 3];
            if (p < 2) acc += w[0] * r[p + 1];   // j=0: in[p+1]
            acc += w[1] * r[p];                  // j=1: in[p]
            if (p > 0) acc += w[2] * r[p - 1];   // j=2: in[p-1]
        }
        dc2[t] = tanhf(acc);
    }
    __syncthreads();

    // ---- deconv3: cat([upsample(dc2)->(4,7), c2]) (8,7) -> (4,7), pad 1, tanh ----
    // upsample index map: q -> dc2 col (q<3?0:(q<5?1:2))  i.e. [0,0,0,1,1,2,2]
    if (t < 28) {
        const int o = t / 7, p = t % 7;
        float acc = DB3[o];
        #pragma unroll
        for (int i = 0; i < 8; ++i) {
            const float* w = &DW3[(i * 4 + o) * 3];
            if (i < 4) {
                const float* r = &dc2[i * 3];
                if (p < 6) { const int q = p + 1; acc += w[0] * r[q < 3 ? 0 : (q < 5 ? 1 : 2)]; }
                {           const int q = p;     acc += w[1] * r[q < 3 ? 0 : (q < 5 ? 1 : 2)]; }
                if (p > 0) { const int q = p - 1; acc += w[2] * r[q < 3 ? 0 : (q < 5 ? 1 : 2)]; }
            } else {
                const float* r = &c2[(i - 4) * 7];
                if (p < 6) acc += w[0] * r[p + 1];
                acc += w[1] * r[p];
                if (p > 0) acc += w[2] * r[p - 1];
            }
        }
        dc3[t] = tanhf(acc);
    }
    __syncthreads();

    // ---- deconv4: cat([dc3, jcat]) (16,7) -> (6,7), pad 1, NO tanh; emit out[2:] ----
    if (t < 42) {
        const int o = t / 7, p = t % 7;
        float acc = DB4[o];
        #pragma unroll
        for (int i = 0; i < 16; ++i) {
            const float* w = &DW4[(i * 6 + o) * 3];
            const float* r = (i < 4) ? &dc3[i * 7] : &jcat[(i - 4) * 7];
            if (p < 6) acc += w[0] * r[p + 1];
            acc += w[1] * r[p];
            if (p > 0) acc += w[2] * r[p - 1];
        }
        if (t >= 2) out[t - 2] = acc;
    }
}

extern "C" void kernel_launch(void* const* d_in, const int* in_sizes, int n_in,
                              void* d_out, int out_size, void* d_ws, size_t ws_size,
                              hipStream_t stream) {
    (void)in_sizes; (void)n_in; (void)out_size; (void)d_ws; (void)ws_size;
    convpolicy14_kernel<<<1, 64, 0, stream>>>(
        (const float*)d_in[0],
        (const float*)d_in[1],  (const float*)d_in[2],
        (const float*)d_in[3],  (const float*)d_in[4],
        (const float*)d_in[5],  (const float*)d_in[6],
        (const float*)d_in[7],  (const float*)d_in[8],
        (const float*)d_in[9],  (const float*)d_in[10],
        (const float*)d_in[11], (const float*)d_in[12],
        (const float*)d_in[13], (const float*)d_in[14],
        (const float*)d_in[15], (const float*)d_in[16],
        (float*)d_out);
}